// Round 10
// baseline (790.440 us; speedup 1.0000x reference)
//
#include <hip/hip_runtime.h>
#include <stdint.h>
#include <math.h>

// ---------------------------------------------------------------------------
// GAT + PairNorm + ReLU, MI355X (gfx950).  Round 18.
// R17 post-mortem: deleting a dispatch+memset moved total 0.5us -> launch
// gaps ~0; batch-4 gather neutral -> agg BW-bound. Floors at spec BW
// predict ~130us vs 271 measured; container sustains ~2.5-3TB/s ->
// kernels are BW-bound at the lower ceiling. Levers = bytes + exposed
// serial phases. This round:
//  * k_redstats + k_finalout fused: red blocks 0..59 (R17 logic, last
//    block finalizes mu/invp, sets ready flag); finalout blocks 60+
//    PRELOAD oa then spin (acquire + s_sleep). Red time hides under
//    finalout's load ramp. colpart moved out->ws (no aliasing).
//  * scatter writes perm_src (coalesced ei[i] read) -> aggregate's
//    per-edge src lookup becomes coalesced; random ei[eid] gone.
// Controls: k_gemm, k_pre untouched.
// RNG: JAX partitionable threefry (fold-like split; bits = o0^o1).
// ---------------------------------------------------------------------------

#define N_NODES 30000
#define MPAD    30080
#define DIM     512
#define NEDGE   300000
#define ETOT    330000
#define AGG_BLOCKS 7500
#define RED_BLOCKS 60
#define RED_ROWS   125
#define FIN_BLOCKS 7500

#define GEMM_BLOCKS 940
#define CVT_BLOCKS  256
#define DROP_BLOCKS 7520
#define HIST_BLOCKS 1290
#define DOT_BLOCKS  118

#define STILES 118   // 118*256 = 30208 >= 30000 (tail guarded)

typedef unsigned int u32;
typedef unsigned short u16;

typedef __attribute__((ext_vector_type(8))) short bf16x8;
typedef __attribute__((ext_vector_type(4))) float f32x4;

// ----------------------------- threefry2x32 --------------------------------
__host__ __device__ __forceinline__ void threefry2x32(u32 k0, u32 k1, u32 x0, u32 x1,
                                                      u32& o0, u32& o1) {
  u32 ks2 = k0 ^ k1 ^ 0x1BD11BDAu;
#define TF_R(r) { x0 += x1; x1 = (x1 << r) | (x1 >> (32 - r)); x1 ^= x0; }
  x0 += k0; x1 += k1;
  TF_R(13) TF_R(15) TF_R(26) TF_R(6)
  x0 += k1; x1 += ks2 + 1u;
  TF_R(17) TF_R(29) TF_R(16) TF_R(24)
  x0 += ks2; x1 += k0 + 2u;
  TF_R(13) TF_R(15) TF_R(26) TF_R(6)
  x0 += k0; x1 += k1 + 3u;
  TF_R(17) TF_R(29) TF_R(16) TF_R(24)
  x0 += k1; x1 += ks2 + 4u;
  TF_R(13) TF_R(15) TF_R(26) TF_R(6)
  x0 += ks2; x1 += k0 + 5u;
#undef TF_R
  o0 = x0; o1 = x1;
}

__device__ __forceinline__ u32 tf_fold(u32 k0, u32 k1, u32 idx) {
  u32 a, b;
  threefry2x32(k0, k1, 0u, idx, a, b);
  return a ^ b;
}

__device__ __forceinline__ float bf2f(u32 bits16) {
  return __uint_as_float(bits16 << 16);
}
__device__ __forceinline__ u16 f2bf(float f) {   // RNE
  u32 u = __float_as_uint(f);
  return (u16)((u + 0x7fffu + ((u >> 16) & 1u)) >> 16);
}

// ---------------- K_pre: fused cvtW + dropout + hist (independent) ---------
__global__ __launch_bounds__(256) void k_pre(const float* __restrict__ W,
                                             u16* __restrict__ Wt,
                                             const float* __restrict__ x,
                                             u16* __restrict__ xd,
                                             const int* __restrict__ ei,
                                             int* __restrict__ counts,
                                             unsigned int* __restrict__ done,
                                             unsigned int* __restrict__ ready,
                                             u32 kf0, u32 kf1) {
  __shared__ u16 tile[32][33];
  int b = blockIdx.x;
  if (b == 0 && threadIdx.x == 0) { *done = 0u; *ready = 0u; }
  if (b < CVT_BLOCKS) {
    // ---- W (fp32) -> Wt (bf16, transposed) ----
    int bk = (b & 15) * 32, bn = (b >> 4) * 32;
    int c = threadIdx.x & 31, r = threadIdx.x >> 5;
#pragma unroll
    for (int rr = 0; rr < 32; rr += 8)
      tile[r + rr][c] = f2bf(W[(size_t)(bk + r + rr) * DIM + bn + c]);
    __syncthreads();
#pragma unroll
    for (int rr = 0; rr < 32; rr += 8)
      Wt[(size_t)(bn + r + rr) * DIM + bk + c] = tile[c][r + rr];
  } else if (b < CVT_BLOCKS + DROP_BLOCKS) {
    // ---- feature dropout (p=0.5) fp32 -> bf16, pad ----
    size_t gid = (size_t)(b - CVT_BLOCKS) * 256 + threadIdx.x;
    size_t i0 = gid * 8;
    if (i0 < (size_t)MPAD * DIM) {
      uint4 o = make_uint4(0u, 0u, 0u, 0u);
      if (i0 < (size_t)N_NODES * DIM) {
        float4 v0 = *(const float4*)(x + i0);
        float4 v1 = *(const float4*)(x + i0 + 4);
        float xv[8] = {v0.x, v0.y, v0.z, v0.w, v1.x, v1.y, v1.z, v1.w};
        u32 res[4];
#pragma unroll
        for (int p = 0; p < 4; p++) {
          u32 b0 = tf_fold(kf0, kf1, (u32)i0 + 2 * p);
          u32 b1 = tf_fold(kf0, kf1, (u32)i0 + 2 * p + 1);
          u32 r0 = (b0 >> 31) ? 0u : (u32)f2bf(2.0f * xv[2 * p]);
          u32 r1 = (b1 >> 31) ? 0u : (u32)f2bf(2.0f * xv[2 * p + 1]);
          res[p] = r0 | (r1 << 16);
        }
        o = make_uint4(res[0], res[1], res[2], res[3]);
      }
      *(uint4*)(xd + i0) = o;
    }
  } else {
    // ---- histogram of dst (with self-loops) ----
    int i = (b - CVT_BLOCKS - DROP_BLOCKS) * 256 + threadIdx.x;
    if (i < ETOT) {
      int d = (i < NEDGE) ? ei[NEDGE + i] : (i - NEDGE);
      atomicAdd(&counts[d], 1);
    }
  }
}

// --------------- K_gemm: scan (block 0) + swizzled GEMM + dots -------------
// h[m][n] = sum_k xd[m][k]*Wt[n][k]. 128x128 tile, 4 waves, BK=32 -- R8's
// proven register round-trip loop (loads issued before barrier 1 = depth-1
// prefetch). Work ids XCD-chunked (m204) so sibling bn-blocks share L2.
__global__ __launch_bounds__(256) void k_gemm(const u16* __restrict__ A,
                                              const u16* __restrict__ B,
                                              u16* __restrict__ H,
                                              const float* __restrict__ atts,
                                              const float* __restrict__ attd,
                                              float* __restrict__ aspart,
                                              float* __restrict__ adpart,
                                              const int* __restrict__ counts,
                                              int* __restrict__ off,
                                              int* __restrict__ cursor) {
  __shared__ __align__(16) u16 lA[128 * 32];
  __shared__ __align__(16) u16 lB[128 * 32];

  if (blockIdx.x == 0) {
    // -------- ILP-batched 3-phase exclusive scan of counts (1 block) ------
    int* tsum = (int*)lA;            // alias gemm LDS (scan path never uses lA)
    int tid = threadIdx.x, lane = tid & 63, wid = tid >> 6;

    // Phase A: tile sums; batches of 8 independent int4 loads in flight.
    for (int t0 = wid; t0 < STILES; t0 += 32) {       // 4 batches per wave
      int4 v[8];
#pragma unroll
      for (int b = 0; b < 8; b++) {
        int t = t0 + b * 4;
        int i = t * 256 + lane * 4;
        if (t < STILES) {
          if (i + 4 <= N_NODES) {
            v[b] = *(const int4*)(counts + i);
          } else {
            v[b].x = (i     < N_NODES) ? counts[i]     : 0;
            v[b].y = (i + 1 < N_NODES) ? counts[i + 1] : 0;
            v[b].z = (i + 2 < N_NODES) ? counts[i + 2] : 0;
            v[b].w = (i + 3 < N_NODES) ? counts[i + 3] : 0;
          }
        } else {
          v[b] = make_int4(0, 0, 0, 0);
        }
      }
#pragma unroll
      for (int b = 0; b < 8; b++) {
        int t = t0 + b * 4;
        if (t < STILES) {
          int s = v[b].x + v[b].y + v[b].z + v[b].w;
#pragma unroll
          for (int d = 1; d < 64; d <<= 1) s += __shfl_xor(s, d);
          if (lane == 0) tsum[t] = s;
        }
      }
    }
    __syncthreads();

    // Phase B: wave 0 exclusive-scans tsum[118] (2 shuffle-scan rounds).
    if (wid == 0) {
      int carry = 0;
#pragma unroll
      for (int r = 0; r < 2; r++) {   // 2*64 = 128 >= 118
        int idx = r * 64 + lane;
        int vv = (idx < STILES) ? tsum[idx] : 0;
        int x = vv;
#pragma unroll
        for (int d = 1; d < 64; d <<= 1) {
          int y = __shfl_up(x, d);
          if (lane >= d) x += y;
        }
        if (idx < STILES) tsum[idx] = x - vv + carry;  // exclusive base
        carry += __shfl(x, 63);
      }
    }
    __syncthreads();

    // Phase C: per-tile exclusive offsets. Same batching as A.
    for (int t0 = wid; t0 < STILES; t0 += 32) {
      int4 v[8];
#pragma unroll
      for (int b = 0; b < 8; b++) {
        int t = t0 + b * 4;
        int i = t * 256 + lane * 4;
        if (t < STILES) {
          if (i + 4 <= N_NODES) {
            v[b] = *(const int4*)(counts + i);
          } else {
            v[b].x = (i     < N_NODES) ? counts[i]     : 0;
            v[b].y = (i + 1 < N_NODES) ? counts[i + 1] : 0;
            v[b].z = (i + 2 < N_NODES) ? counts[i + 2] : 0;
            v[b].w = (i + 3 < N_NODES) ? counts[i + 3] : 0;
          }
        } else {
          v[b] = make_int4(0, 0, 0, 0);
        }
      }
#pragma unroll
      for (int b = 0; b < 8; b++) {
        int t = t0 + b * 4;
        if (t >= STILES) continue;
        int i = t * 256 + lane * 4;
        int s4 = v[b].x + v[b].y + v[b].z + v[b].w;
        int x = s4;
#pragma unroll
        for (int d = 1; d < 64; d <<= 1) {
          int y = __shfl_up(x, d);
          if (lane >= d) x += y;
        }
        int base = tsum[t] + (x - s4);       // exclusive across lanes
        int4 e;
        e.x = base;
        e.y = base + v[b].x;
        e.z = e.y + v[b].y;
        e.w = e.z + v[b].z;
        if (i + 4 <= N_NODES) {
          *(int4*)(off + i) = e;
          *(int4*)(cursor + i) = e;
        } else {
          if (i     < N_NODES) { off[i]     = e.x; cursor[i]     = e.x; }
          if (i + 1 < N_NODES) { off[i + 1] = e.y; cursor[i + 1] = e.y; }
          if (i + 2 < N_NODES) { off[i + 2] = e.z; cursor[i + 2] = e.z; }
          if (i + 3 < N_NODES) { off[i + 3] = e.w; cursor[i + 3] = e.w; }
        }
      }
    }
    if (tid == 0) off[N_NODES] = ETOT;
    return;
  }

  // ---- XCD-chunked work id (m204 bijective; nwg=940: q=117, r=4).
  const int g = blockIdx.x - 1;               // 0..939
  const int xcd = g & 7, gi = g >> 3;
  const int wrk = (xcd < 4 ? xcd * 118 : 472 + (xcd - 4) * 117) + gi;

  const int bn = (wrk & 3) * 128;
  const int bm = (wrk >> 2) * 128;
  const int tid = threadIdx.x;
  const int wave = tid >> 6, lane = tid & 63;
  const int quad = lane >> 4, l16 = lane & 15;
  const int wrow = (wave & 1) * 64, wcol = (wave >> 1) * 64;

  f32x4 acc[4][4] = {};
  const int srow = tid >> 2;
  const int scq  = (tid & 3) * 8;

  for (int k0 = 0; k0 < DIM; k0 += 32) {
    uint4 va0 = *(const uint4*)(A + (size_t)(bm + srow) * DIM + k0 + scq);
    uint4 va1 = *(const uint4*)(A + (size_t)(bm + 64 + srow) * DIM + k0 + scq);
    uint4 vb0 = *(const uint4*)(B + (size_t)(bn + srow) * DIM + k0 + scq);
    uint4 vb1 = *(const uint4*)(B + (size_t)(bn + 64 + srow) * DIM + k0 + scq);
    __syncthreads();
    *(uint4*)(lA + srow * 32 + scq) = va0;
    *(uint4*)(lA + (64 + srow) * 32 + scq) = va1;
    *(uint4*)(lB + srow * 32 + scq) = vb0;
    *(uint4*)(lB + (64 + srow) * 32 + scq) = vb1;
    __syncthreads();

    bf16x8 af[4], bfr[4];
#pragma unroll
    for (int i = 0; i < 4; i++)
      af[i] = *(const bf16x8*)(lA + (wrow + i * 16 + l16) * 32 + quad * 8);
#pragma unroll
    for (int j = 0; j < 4; j++)
      bfr[j] = *(const bf16x8*)(lB + (wcol + j * 16 + l16) * 32 + quad * 8);
#pragma unroll
    for (int i = 0; i < 4; i++)
#pragma unroll
      for (int j = 0; j < 4; j++)
        acc[i][j] = __builtin_amdgcn_mfma_f32_16x16x32_bf16(af[i], bfr[j], acc[i][j], 0, 0, 0);
  }

  // ---- epilogue: H write (C/D: col=lane&15, row=quad*4+reg) ----
#pragma unroll
  for (int i = 0; i < 4; i++) {
#pragma unroll
    for (int r = 0; r < 4; r++) {
      int row = bm + wrow + i * 16 + quad * 4 + r;
      u16* hp = H + (size_t)row * DIM + bn + wcol + l16;
#pragma unroll
      for (int j = 0; j < 4; j++) hp[j * 16] = f2bf(acc[i][j][r]);
    }
  }

  // ---- fused attention dots: partial over this wave's 64 cols ----
  float as_j[4], ad_j[4];
#pragma unroll
  for (int j = 0; j < 4; j++) {
    int col = bn + wcol + j * 16 + l16;
    as_j[j] = atts[col];
    ad_j[j] = attd[col];
  }
  int slot = ((bn >> 7) << 1) + (wcol >> 6);   // 0..7
#pragma unroll
  for (int i = 0; i < 4; i++) {
#pragma unroll
    for (int r = 0; r < 4; r++) {
      float ps = acc[i][0][r] * as_j[0] + acc[i][1][r] * as_j[1]
               + acc[i][2][r] * as_j[2] + acc[i][3][r] * as_j[3];
      float pd = acc[i][0][r] * ad_j[0] + acc[i][1][r] * ad_j[1]
               + acc[i][2][r] * ad_j[2] + acc[i][3][r] * ad_j[3];
#pragma unroll
      for (int d = 1; d < 16; d <<= 1) {
        ps += __shfl_xor(ps, d);
        pd += __shfl_xor(pd, d);
      }
      int row = bm + wrow + i * 16 + quad * 4 + r;
      if (l16 == 0) {
        aspart[slot * MPAD + row] = ps;
        adpart[slot * MPAD + row] = pd;
      }
    }
  }
}

// -------- K_mid: fused dotsum + scatter (writes perm AND perm_src) ---------
__global__ __launch_bounds__(256) void k_mid(const float* __restrict__ aspart,
                                             const float* __restrict__ adpart,
                                             float* __restrict__ a_s,
                                             float* __restrict__ a_d,
                                             const int* __restrict__ ei,
                                             int* __restrict__ cursor,
                                             int* __restrict__ perm,
                                             int* __restrict__ perm_src) {
  int b = blockIdx.x;
  if (b < DOT_BLOCKS) {
    int i = b * 256 + threadIdx.x;
    if (i < N_NODES) {
      float s = 0.f, d = 0.f;
#pragma unroll
      for (int k = 0; k < 8; k++) {
        s += aspart[k * MPAD + i];
        d += adpart[k * MPAD + i];
      }
      a_s[i] = s;
      a_d[i] = d;
    }
  } else {
    int i = (b - DOT_BLOCKS) * 256 + threadIdx.x;
    if (i < ETOT) {
      int d   = (i < NEDGE) ? ei[NEDGE + i] : (i - NEDGE);
      int src = (i < NEDGE) ? ei[i]         : (i - NEDGE);   // coalesced
      int slot = atomicAdd(&cursor[d], 1);
      perm[slot] = i;
      perm_src[slot] = src;
    }
  }
}

// ----- K7: segment softmax + attention dropout + aggregation + stats -------
// oa stored bf16; column/ssq stats computed on the quantized values.
__global__ __launch_bounds__(256) void k_aggregate(
    const int* __restrict__ off, const int* __restrict__ perm,
    const int* __restrict__ perm_src,
    const float* __restrict__ a_s, const float* __restrict__ a_d,
    const u16* __restrict__ h, const float* __restrict__ bias,
    u16* __restrict__ oa, float* __restrict__ colpart,
    float* __restrict__ ssqpart, u32 ka0, u32 ka1) {
  __shared__ float lbuf[4][512];
  int wid = threadIdx.x >> 6;
  int node = blockIdx.x * 4 + wid;
  int lane = threadIdx.x & 63;
  int beg = off[node], end = off[node + 1];
  int deg = end - beg;
  float adn = a_d[node];

  float acc[8] = {0.f, 0.f, 0.f, 0.f, 0.f, 0.f, 0.f, 0.f};

  if (deg <= 64) {
    int idx = beg + lane;
    bool valid = idx < end;
    int s = 0;
    float lg = -3.0e38f;
    u32 keepbits = 0;
    if (valid) {
      int eid = perm[idx];
      s = perm_src[idx];                       // coalesced (was random ei[eid])
      lg = a_s[s] + adn;
      lg = (lg < 0.f) ? 0.2f * lg : lg;
      keepbits = tf_fold(ka0, ka1, (u32)eid);
    }
    float mx = lg;
#pragma unroll
    for (int d = 1; d < 64; d <<= 1) mx = fmaxf(mx, __shfl_xor(mx, d));
    float ee = valid ? expf(lg - mx) : 0.f;
    float ssum = ee;
#pragma unroll
    for (int d = 1; d < 64; d <<= 1) ssum += __shfl_xor(ssum, d);
    float inv_s = 2.5f / (ssum + 1e-16f);
    float w = (valid && ((keepbits >> 9) < 3355444u)) ? ee * inv_s : 0.f;

    // batch-4 ILP gather: 4 independent 1KB row loads in flight.
    int j = 0;
    for (; j + 4 <= deg; j += 4) {
      float wj[4]; int sj[4]; uint4 hv[4];
#pragma unroll
      for (int bq = 0; bq < 4; bq++) {
        wj[bq] = __shfl(w, j + bq);
        sj[bq] = __shfl(s, j + bq);
      }
#pragma unroll
      for (int bq = 0; bq < 4; bq++)
        if (wj[bq] != 0.f)
          hv[bq] = *(const uint4*)(h + (size_t)sj[bq] * DIM + lane * 8);
#pragma unroll
      for (int bq = 0; bq < 4; bq++) {
        if (wj[bq] != 0.f) {
          u32 hw[4] = {hv[bq].x, hv[bq].y, hv[bq].z, hv[bq].w};
#pragma unroll
          for (int p = 0; p < 4; p++) {
            acc[2 * p]     += wj[bq] * bf2f(hw[p] & 0xffffu);
            acc[2 * p + 1] += wj[bq] * bf2f(hw[p] >> 16);
          }
        }
      }
    }
    for (; j < deg; j++) {
      float wjv = __shfl(w, j);
      if (wjv != 0.f) {
        int sjv = __shfl(s, j);
        uint4 hvv = *(const uint4*)(h + (size_t)sjv * DIM + lane * 8);
        u32 hw[4] = {hvv.x, hvv.y, hvv.z, hvv.w};
#pragma unroll
        for (int p = 0; p < 4; p++) {
          acc[2 * p]     += wjv * bf2f(hw[p] & 0xffffu);
          acc[2 * p + 1] += wjv * bf2f(hw[p] >> 16);
        }
      }
    }
  } else {
    float mx = -3.0e38f;
    for (int base = beg; base < end; base += 64) {
      int idx = base + lane;
      if (idx < end) {
        int s = perm_src[idx];
        float lg = a_s[s] + adn;
        lg = (lg < 0.f) ? 0.2f * lg : lg;
        mx = fmaxf(mx, lg);
      }
    }
#pragma unroll
    for (int d = 1; d < 64; d <<= 1) mx = fmaxf(mx, __shfl_xor(mx, d));
    float ssum = 0.f;
    for (int base = beg; base < end; base += 64) {
      int idx = base + lane;
      if (idx < end) {
        int s = perm_src[idx];
        float lg = a_s[s] + adn;
        lg = (lg < 0.f) ? 0.2f * lg : lg;
        ssum += expf(lg - mx);
      }
    }
#pragma unroll
    for (int d = 1; d < 64; d <<= 1) ssum += __shfl_xor(ssum, d);
    float inv_s = 2.5f / (ssum + 1e-16f);
    for (int base = beg; base < end; base += 64) {
      int idx = base + lane;
      float w = 0.f; int s = 0;
      if (idx < end) {
        int eid = perm[idx];
        s = perm_src[idx];
        float lg = a_s[s] + adn;
        lg = (lg < 0.f) ? 0.2f * lg : lg;
        float ee = expf(lg - mx);
        u32 bits = tf_fold(ka0, ka1, (u32)eid);
        if ((bits >> 9) < 3355444u) w = ee * inv_s;
      }
      int cnt = min(64, end - base);
      for (int j = 0; j < cnt; j++) {
        float wj = __shfl(w, j);
        if (wj != 0.f) {
          int sj = __shfl(s, j);
          uint4 hv = *(const uint4*)(h + (size_t)sj * DIM + lane * 8);
          u32 hw[4] = {hv.x, hv.y, hv.z, hv.w};
#pragma unroll
          for (int p = 0; p < 4; p++) {
            acc[2 * p]     += wj * bf2f(hw[p] & 0xffffu);
            acc[2 * p + 1] += wj * bf2f(hw[p] >> 16);
          }
        }
      }
    }
  }

  // epilogue: add bias, quantize to bf16, store oa, stats on quantized vals
  float4 b0 = *(const float4*)(bias + lane * 8);
  float4 b1 = *(const float4*)(bias + lane * 8 + 4);
  float bb[8] = {b0.x, b0.y, b0.z, b0.w, b1.x, b1.y, b1.z, b1.w};
  u32 res[4];
  float vq[8];
#pragma unroll
  for (int p = 0; p < 4; p++) {
    u16 q0 = f2bf(acc[2 * p]     + bb[2 * p]);
    u16 q1 = f2bf(acc[2 * p + 1] + bb[2 * p + 1]);
    res[p] = (u32)q0 | ((u32)q1 << 16);
    vq[2 * p]     = bf2f(q0);
    vq[2 * p + 1] = bf2f(q1);
  }
  *(uint4*)(oa + (size_t)node * DIM + lane * 8) = make_uint4(res[0], res[1], res[2], res[3]);
  *(float4*)&lbuf[wid][lane * 8]     = make_float4(vq[0], vq[1], vq[2], vq[3]);
  *(float4*)&lbuf[wid][lane * 8 + 4] = make_float4(vq[4], vq[5], vq[6], vq[7]);
  __syncthreads();

  int t = threadIdx.x;
  float s0 = 0.f, s1 = 0.f, ssl = 0.f;
#pragma unroll
  for (int w = 0; w < 4; w++) {
    float a = lbuf[w][t], b = lbuf[w][t + 256];
    s0 += a; s1 += b;
    ssl = fmaf(a, a, ssl);
    ssl = fmaf(b, b, ssl);
  }
  colpart[(size_t)blockIdx.x * 512 + t]       = s0;
  colpart[(size_t)blockIdx.x * 512 + 256 + t] = s1;
#pragma unroll
  for (int d = 1; d < 64; d <<= 1) ssl += __shfl_xor(ssl, d);
  __shared__ float wss[4];
  if ((t & 63) == 0) wss[t >> 6] = ssl;
  __syncthreads();
  if (t == 0) ssqpart[blockIdx.x] = wss[0] + wss[1] + wss[2] + wss[3];
}

// ---- K_final: redstats (blocks 0..59, last finalizes) + finalout (60+) ----
// finalout blocks PRELOAD their oa data, then spin on ready (set by the
// finalizer after mu/invp are written). Dispatch order => red blocks get
// CUs first; no deadlock. All colpart reads precede any out write.
__global__ __launch_bounds__(256) void k_final(const float* __restrict__ colpart,
                                               const float* __restrict__ ssqpart,
                                               float* __restrict__ colpart2,
                                               double* __restrict__ ssqp2,
                                               unsigned int* __restrict__ done,
                                               unsigned int* __restrict__ ready,
                                               float* __restrict__ mu,
                                               float* __restrict__ invp,
                                               const u16* __restrict__ oa,
                                               float* __restrict__ out) {
  int t = threadIdx.x;
  if (blockIdx.x < RED_BLOCKS) {
    int b = blockIdx.x;
    int r0 = b * RED_ROWS;
    float s0 = 0.f, s1 = 0.f;
    for (int r = r0; r < r0 + RED_ROWS; r++) {
      s0 += colpart[(size_t)r * 512 + t];
      s1 += colpart[(size_t)r * 512 + 256 + t];
    }
    colpart2[(size_t)b * 512 + t]       = s0;
    colpart2[(size_t)b * 512 + 256 + t] = s1;
    float sl = (t < RED_ROWS) ? ssqpart[r0 + t] : 0.f;
#pragma unroll
    for (int d = 1; d < 64; d <<= 1) sl += __shfl_xor(sl, d);
    __shared__ float w4[4];
    if ((t & 63) == 0) w4[t >> 6] = sl;
    __syncthreads();
    if (t == 0) ssqp2[b] = (double)(w4[0] + w4[1] + w4[2] + w4[3]);

    __threadfence();
    __syncthreads();
    __shared__ unsigned int olds;
    if (t == 0) olds = atomicAdd(done, 1u);
    __syncthreads();
    if (olds == RED_BLOCKS - 1) {
      __threadfence();
      float m0 = 0.f, m1 = 0.f;
      for (int r = 0; r < RED_BLOCKS; r++) {
        m0 += colpart2[(size_t)r * 512 + t];
        m1 += colpart2[(size_t)r * 512 + 256 + t];
      }
      m0 *= (1.0f / 30000.0f);
      m1 *= (1.0f / 30000.0f);
      mu[t]       = m0;
      mu[t + 256] = m1;
      double p = (double)m0 * (double)m0 + (double)m1 * (double)m1;
#pragma unroll
      for (int d = 1; d < 64; d <<= 1) p += __shfl_xor(p, d);
      __shared__ double sred[4];
      __shared__ double ssqs;
      if ((t & 63) == 0) sred[t >> 6] = p;
      if (t < 64) {
        double sq = (t < RED_BLOCKS) ? ssqp2[t] : 0.0;
#pragma unroll
        for (int d = 1; d < 64; d <<= 1) sq += __shfl_xor(sq, d);
        if (t == 0) ssqs = sq;
      }
      __syncthreads();
      if (t == 0) {
        double smu2 = sred[0] + sred[1] + sred[2] + sred[3];
        double centered = ssqs - 30000.0 * smu2;
        double mean = centered * (1.0 / 30000.0);
        if (!(mean >= 0.0)) mean = 0.0;
        float rn = sqrtf(1e-6f + (float)mean);
        invp[0] = 1.0f / rn;
        __threadfence();
        atomicExch(ready, 1u);
      }
    }
    return;
  }

  // ---------------- finalout: preload -> spin -> compute -----------------
  size_t gid = (size_t)(blockIdx.x - RED_BLOCKS) * 256 + t;
  size_t i0 = gid * 8;                 // FIN_BLOCKS*2048 == N*D exactly
  uint4 v = *(const uint4*)(oa + i0);  // preload under redstats' runtime
  if (t == 0) {
    while (__hip_atomic_load(ready, __ATOMIC_ACQUIRE, __HIP_MEMORY_SCOPE_AGENT) == 0u)
      __builtin_amdgcn_s_sleep(16);
  }
  __syncthreads();
  float inv = invp[0];
  int j = (int)(i0 & (DIM - 1));
  u32 w[4] = {v.x, v.y, v.z, v.w};
  float o[8];
#pragma unroll
  for (int p = 0; p < 4; p++) {
    float z0 = (bf2f(w[p] & 0xffffu) - mu[j + 2 * p]) * inv;
    float z1 = (bf2f(w[p] >> 16)     - mu[j + 2 * p + 1]) * inv;
    o[2 * p]     = (z0 < 0.f) ? 0.f : z0;
    o[2 * p + 1] = (z1 < 0.f) ? 0.f : z1;
  }
  *(float4*)(out + i0)     = make_float4(o[0], o[1], o[2], o[3]);
  *(float4*)(out + i0 + 4) = make_float4(o[4], o[5], o[6], o[7]);
}

// ---------------------------------------------------------------------------
extern "C" void kernel_launch(void* const* d_in, const int* in_sizes, int n_in,
                              void* d_out, int out_size, void* d_ws, size_t ws_size,
                              hipStream_t stream) {
  const float* x    = (const float*)d_in[0];
  const int*   ei   = (const int*)d_in[1];
  const float* W    = (const float*)d_in[2];
  const float* atts = (const float*)d_in[3];
  const float* attd = (const float*)d_in[4];
  const float* bias = (const float*)d_in[5];
  float* out = (float*)d_out;
  char* ws = (char*)d_ws;

  // oa overlays xd at ws+0 (xd dead after gemm). colpart/ssqpart/perm_src
  // live in the [34M, 61.44M) dead gap (colpart moved out of d_out so
  // k_final's out-writes never alias red reads).
  u16*   xd      = (u16*)(ws + 0);             // 30,801,920
  u16*   oa      = (u16*)(ws + 0);             // 30,720,000 (overlay)
  float* aspart  = (float*)(ws + 32000000);    //   962,560
  float* adpart  = (float*)(ws + 33000000);    //   962,560
  float* colpart2 = (float*)(ws + 34000000);   //   122,880
  double* ssqp2  = (double*)(ws + 34130000);   //       480
  unsigned int* done  = (unsigned int*)(ws + 34140000);   // 4
  unsigned int* ready = (unsigned int*)(ws + 34140064);   // 4
  float* colpart = (float*)(ws + 35000000);    // 7500*512*4 = 15,360,000
  float* ssqpart = (float*)(ws + 50500000);    //    30,000
  int*   perm_src = (int*)(ws + 51000000);     // 1,320,000 -> 52.32M
  u16*   h       = (u16*)(ws + 61440000);      // 30,801,920
  u16*   Wt      = (u16*)(ws + 92241920);      //    524,288
  float* a_s     = (float*)(ws + 92766208);    //    120,064
  float* a_d     = (float*)(ws + 92886272);    //    120,064
  int*   counts  = (int*)(ws + 93006336);
  int*   offs    = (int*)(ws + 93126400);
  int*   cursor  = (int*)(ws + 93246464);
  int*   perm    = (int*)(ws + 93366528);      //  1,320,000
  float* mu      = (float*)(ws + 94688576);
  float* invp    = (float*)(ws + 94690688);    // end 94,690,752

  u32 kf0, kf1, ka0, ka1;
  threefry2x32(0u, 42u, 0u, 0u, kf0, kf1);
  threefry2x32(0u, 42u, 0u, 1u, ka0, ka1);

  hipMemsetAsync(counts, 0, 120064, stream);

  // L1: cvtW + dropout + hist; block 0 resets done/ready flags.
  k_pre<<<CVT_BLOCKS + DROP_BLOCKS + HIST_BLOCKS, 256, 0, stream>>>(
      W, Wt, x, xd, ei, counts, done, ready, kf0, kf1);
  // L2: scan (block 0) + swizzled gemm (blocks 1..940)
  k_gemm<<<GEMM_BLOCKS + 1, 256, 0, stream>>>(xd, Wt, h, atts, attd,
                                              aspart, adpart, counts, offs, cursor);
  // L3: dotsum + scatter (perm + perm_src)
  k_mid<<<DOT_BLOCKS + HIST_BLOCKS, 256, 0, stream>>>(aspart, adpart, a_s, a_d,
                                                      ei, cursor, perm, perm_src);
  // L4: aggregate (stats -> ws colpart/ssqpart)
  k_aggregate<<<AGG_BLOCKS, 256, 0, stream>>>(offs, perm, perm_src, a_s, a_d,
                                              h, bias, oa, colpart, ssqpart,
                                              ka0, ka1);
  // L5: fused redstats + finalize + finalout (preload/spin)
  k_final<<<RED_BLOCKS + FIN_BLOCKS, 256, 0, stream>>>(colpart, ssqpart,
                                                       colpart2, ssqp2, done,
                                                       ready, mu, invp, oa, out);
}

// Round 11
// 269.701 us; speedup vs baseline: 2.9308x; 2.9308x over previous
//
#include <hip/hip_runtime.h>
#include <stdint.h>
#include <math.h>

// ---------------------------------------------------------------------------
// GAT + PairNorm + ReLU, MI355X (gfx950).  Round 19.
// R18 post-mortem: fused red+finalout via global spin flag = 573us
// meltdown -- ~2000 co-resident blocks polling one cache line with
// device-scope atomics serialize the coherence point; the producer's own
// fenced writes crawl through the same path. LESSON: cross-block
// pipelining via spin flags is a non-starter at this block count;
// separate dispatches cost ~0 (measured R17). Revert to R17 structure.
// KEEP from R18 (orthogonal, verified): perm_src (coalesced src lookup
// in aggregate), colpart in ws (no d_out aliasing).
// RNG: JAX partitionable threefry (fold-like split; bits = o0^o1).
// ---------------------------------------------------------------------------

#define N_NODES 30000
#define MPAD    30080
#define DIM     512
#define NEDGE   300000
#define ETOT    330000
#define AGG_BLOCKS 7500
#define RED_BLOCKS 60
#define RED_ROWS   125

#define GEMM_BLOCKS 940
#define CVT_BLOCKS  256
#define DROP_BLOCKS 7520
#define HIST_BLOCKS 1290
#define DOT_BLOCKS  118

#define STILES 118   // 118*256 = 30208 >= 30000 (tail guarded)

typedef unsigned int u32;
typedef unsigned short u16;

typedef __attribute__((ext_vector_type(8))) short bf16x8;
typedef __attribute__((ext_vector_type(4))) float f32x4;

// ----------------------------- threefry2x32 --------------------------------
__host__ __device__ __forceinline__ void threefry2x32(u32 k0, u32 k1, u32 x0, u32 x1,
                                                      u32& o0, u32& o1) {
  u32 ks2 = k0 ^ k1 ^ 0x1BD11BDAu;
#define TF_R(r) { x0 += x1; x1 = (x1 << r) | (x1 >> (32 - r)); x1 ^= x0; }
  x0 += k0; x1 += k1;
  TF_R(13) TF_R(15) TF_R(26) TF_R(6)
  x0 += k1; x1 += ks2 + 1u;
  TF_R(17) TF_R(29) TF_R(16) TF_R(24)
  x0 += ks2; x1 += k0 + 2u;
  TF_R(13) TF_R(15) TF_R(26) TF_R(6)
  x0 += k0; x1 += k1 + 3u;
  TF_R(17) TF_R(29) TF_R(16) TF_R(24)
  x0 += k1; x1 += ks2 + 4u;
  TF_R(13) TF_R(15) TF_R(26) TF_R(6)
  x0 += ks2; x1 += k0 + 5u;
#undef TF_R
  o0 = x0; o1 = x1;
}

__device__ __forceinline__ u32 tf_fold(u32 k0, u32 k1, u32 idx) {
  u32 a, b;
  threefry2x32(k0, k1, 0u, idx, a, b);
  return a ^ b;
}

__device__ __forceinline__ float bf2f(u32 bits16) {
  return __uint_as_float(bits16 << 16);
}
__device__ __forceinline__ u16 f2bf(float f) {   // RNE
  u32 u = __float_as_uint(f);
  return (u16)((u + 0x7fffu + ((u >> 16) & 1u)) >> 16);
}

// ---------------- K_pre: fused cvtW + dropout + hist (independent) ---------
__global__ __launch_bounds__(256) void k_pre(const float* __restrict__ W,
                                             u16* __restrict__ Wt,
                                             const float* __restrict__ x,
                                             u16* __restrict__ xd,
                                             const int* __restrict__ ei,
                                             int* __restrict__ counts,
                                             unsigned int* __restrict__ done,
                                             u32 kf0, u32 kf1) {
  __shared__ u16 tile[32][33];
  int b = blockIdx.x;
  if (b == 0 && threadIdx.x == 0) *done = 0u;   // reset redstats counter
  if (b < CVT_BLOCKS) {
    // ---- W (fp32) -> Wt (bf16, transposed) ----
    int bk = (b & 15) * 32, bn = (b >> 4) * 32;
    int c = threadIdx.x & 31, r = threadIdx.x >> 5;
#pragma unroll
    for (int rr = 0; rr < 32; rr += 8)
      tile[r + rr][c] = f2bf(W[(size_t)(bk + r + rr) * DIM + bn + c]);
    __syncthreads();
#pragma unroll
    for (int rr = 0; rr < 32; rr += 8)
      Wt[(size_t)(bn + r + rr) * DIM + bk + c] = tile[c][r + rr];
  } else if (b < CVT_BLOCKS + DROP_BLOCKS) {
    // ---- feature dropout (p=0.5) fp32 -> bf16, pad ----
    size_t gid = (size_t)(b - CVT_BLOCKS) * 256 + threadIdx.x;
    size_t i0 = gid * 8;
    if (i0 < (size_t)MPAD * DIM) {
      uint4 o = make_uint4(0u, 0u, 0u, 0u);
      if (i0 < (size_t)N_NODES * DIM) {
        float4 v0 = *(const float4*)(x + i0);
        float4 v1 = *(const float4*)(x + i0 + 4);
        float xv[8] = {v0.x, v0.y, v0.z, v0.w, v1.x, v1.y, v1.z, v1.w};
        u32 res[4];
#pragma unroll
        for (int p = 0; p < 4; p++) {
          u32 b0 = tf_fold(kf0, kf1, (u32)i0 + 2 * p);
          u32 b1 = tf_fold(kf0, kf1, (u32)i0 + 2 * p + 1);
          u32 r0 = (b0 >> 31) ? 0u : (u32)f2bf(2.0f * xv[2 * p]);
          u32 r1 = (b1 >> 31) ? 0u : (u32)f2bf(2.0f * xv[2 * p + 1]);
          res[p] = r0 | (r1 << 16);
        }
        o = make_uint4(res[0], res[1], res[2], res[3]);
      }
      *(uint4*)(xd + i0) = o;
    }
  } else {
    // ---- histogram of dst (with self-loops) ----
    int i = (b - CVT_BLOCKS - DROP_BLOCKS) * 256 + threadIdx.x;
    if (i < ETOT) {
      int d = (i < NEDGE) ? ei[NEDGE + i] : (i - NEDGE);
      atomicAdd(&counts[d], 1);
    }
  }
}

// --------------- K_gemm: scan (block 0) + swizzled GEMM + dots -------------
// h[m][n] = sum_k xd[m][k]*Wt[n][k]. 128x128 tile, 4 waves, BK=32 -- R8's
// proven register round-trip loop (loads issued before barrier 1 = depth-1
// prefetch). Work ids XCD-chunked (m204) so sibling bn-blocks share L2.
__global__ __launch_bounds__(256) void k_gemm(const u16* __restrict__ A,
                                              const u16* __restrict__ B,
                                              u16* __restrict__ H,
                                              const float* __restrict__ atts,
                                              const float* __restrict__ attd,
                                              float* __restrict__ aspart,
                                              float* __restrict__ adpart,
                                              const int* __restrict__ counts,
                                              int* __restrict__ off,
                                              int* __restrict__ cursor) {
  __shared__ __align__(16) u16 lA[128 * 32];
  __shared__ __align__(16) u16 lB[128 * 32];

  if (blockIdx.x == 0) {
    // -------- ILP-batched 3-phase exclusive scan of counts (1 block) ------
    int* tsum = (int*)lA;            // alias gemm LDS (scan path never uses lA)
    int tid = threadIdx.x, lane = tid & 63, wid = tid >> 6;

    // Phase A: tile sums; batches of 8 independent int4 loads in flight.
    for (int t0 = wid; t0 < STILES; t0 += 32) {       // 4 batches per wave
      int4 v[8];
#pragma unroll
      for (int b = 0; b < 8; b++) {
        int t = t0 + b * 4;
        int i = t * 256 + lane * 4;
        if (t < STILES) {
          if (i + 4 <= N_NODES) {
            v[b] = *(const int4*)(counts + i);
          } else {
            v[b].x = (i     < N_NODES) ? counts[i]     : 0;
            v[b].y = (i + 1 < N_NODES) ? counts[i + 1] : 0;
            v[b].z = (i + 2 < N_NODES) ? counts[i + 2] : 0;
            v[b].w = (i + 3 < N_NODES) ? counts[i + 3] : 0;
          }
        } else {
          v[b] = make_int4(0, 0, 0, 0);
        }
      }
#pragma unroll
      for (int b = 0; b < 8; b++) {
        int t = t0 + b * 4;
        if (t < STILES) {
          int s = v[b].x + v[b].y + v[b].z + v[b].w;
#pragma unroll
          for (int d = 1; d < 64; d <<= 1) s += __shfl_xor(s, d);
          if (lane == 0) tsum[t] = s;
        }
      }
    }
    __syncthreads();

    // Phase B: wave 0 exclusive-scans tsum[118] (2 shuffle-scan rounds).
    if (wid == 0) {
      int carry = 0;
#pragma unroll
      for (int r = 0; r < 2; r++) {   // 2*64 = 128 >= 118
        int idx = r * 64 + lane;
        int vv = (idx < STILES) ? tsum[idx] : 0;
        int x = vv;
#pragma unroll
        for (int d = 1; d < 64; d <<= 1) {
          int y = __shfl_up(x, d);
          if (lane >= d) x += y;
        }
        if (idx < STILES) tsum[idx] = x - vv + carry;  // exclusive base
        carry += __shfl(x, 63);
      }
    }
    __syncthreads();

    // Phase C: per-tile exclusive offsets. Same batching as A.
    for (int t0 = wid; t0 < STILES; t0 += 32) {
      int4 v[8];
#pragma unroll
      for (int b = 0; b < 8; b++) {
        int t = t0 + b * 4;
        int i = t * 256 + lane * 4;
        if (t < STILES) {
          if (i + 4 <= N_NODES) {
            v[b] = *(const int4*)(counts + i);
          } else {
            v[b].x = (i     < N_NODES) ? counts[i]     : 0;
            v[b].y = (i + 1 < N_NODES) ? counts[i + 1] : 0;
            v[b].z = (i + 2 < N_NODES) ? counts[i + 2] : 0;
            v[b].w = (i + 3 < N_NODES) ? counts[i + 3] : 0;
          }
        } else {
          v[b] = make_int4(0, 0, 0, 0);
        }
      }
#pragma unroll
      for (int b = 0; b < 8; b++) {
        int t = t0 + b * 4;
        if (t >= STILES) continue;
        int i = t * 256 + lane * 4;
        int s4 = v[b].x + v[b].y + v[b].z + v[b].w;
        int x = s4;
#pragma unroll
        for (int d = 1; d < 64; d <<= 1) {
          int y = __shfl_up(x, d);
          if (lane >= d) x += y;
        }
        int base = tsum[t] + (x - s4);       // exclusive across lanes
        int4 e;
        e.x = base;
        e.y = base + v[b].x;
        e.z = e.y + v[b].y;
        e.w = e.z + v[b].z;
        if (i + 4 <= N_NODES) {
          *(int4*)(off + i) = e;
          *(int4*)(cursor + i) = e;
        } else {
          if (i     < N_NODES) { off[i]     = e.x; cursor[i]     = e.x; }
          if (i + 1 < N_NODES) { off[i + 1] = e.y; cursor[i + 1] = e.y; }
          if (i + 2 < N_NODES) { off[i + 2] = e.z; cursor[i + 2] = e.z; }
          if (i + 3 < N_NODES) { off[i + 3] = e.w; cursor[i + 3] = e.w; }
        }
      }
    }
    if (tid == 0) off[N_NODES] = ETOT;
    return;
  }

  // ---- XCD-chunked work id (m204 bijective; nwg=940: q=117, r=4).
  const int g = blockIdx.x - 1;               // 0..939
  const int xcd = g & 7, gi = g >> 3;
  const int wrk = (xcd < 4 ? xcd * 118 : 472 + (xcd - 4) * 117) + gi;

  const int bn = (wrk & 3) * 128;
  const int bm = (wrk >> 2) * 128;
  const int tid = threadIdx.x;
  const int wave = tid >> 6, lane = tid & 63;
  const int quad = lane >> 4, l16 = lane & 15;
  const int wrow = (wave & 1) * 64, wcol = (wave >> 1) * 64;

  f32x4 acc[4][4] = {};
  const int srow = tid >> 2;
  const int scq  = (tid & 3) * 8;

  for (int k0 = 0; k0 < DIM; k0 += 32) {
    uint4 va0 = *(const uint4*)(A + (size_t)(bm + srow) * DIM + k0 + scq);
    uint4 va1 = *(const uint4*)(A + (size_t)(bm + 64 + srow) * DIM + k0 + scq);
    uint4 vb0 = *(const uint4*)(B + (size_t)(bn + srow) * DIM + k0 + scq);
    uint4 vb1 = *(const uint4*)(B + (size_t)(bn + 64 + srow) * DIM + k0 + scq);
    __syncthreads();
    *(uint4*)(lA + srow * 32 + scq) = va0;
    *(uint4*)(lA + (64 + srow) * 32 + scq) = va1;
    *(uint4*)(lB + srow * 32 + scq) = vb0;
    *(uint4*)(lB + (64 + srow) * 32 + scq) = vb1;
    __syncthreads();

    bf16x8 af[4], bfr[4];
#pragma unroll
    for (int i = 0; i < 4; i++)
      af[i] = *(const bf16x8*)(lA + (wrow + i * 16 + l16) * 32 + quad * 8);
#pragma unroll
    for (int j = 0; j < 4; j++)
      bfr[j] = *(const bf16x8*)(lB + (wcol + j * 16 + l16) * 32 + quad * 8);
#pragma unroll
    for (int i = 0; i < 4; i++)
#pragma unroll
      for (int j = 0; j < 4; j++)
        acc[i][j] = __builtin_amdgcn_mfma_f32_16x16x32_bf16(af[i], bfr[j], acc[i][j], 0, 0, 0);
  }

  // ---- epilogue: H write (C/D: col=lane&15, row=quad*4+reg) ----
#pragma unroll
  for (int i = 0; i < 4; i++) {
#pragma unroll
    for (int r = 0; r < 4; r++) {
      int row = bm + wrow + i * 16 + quad * 4 + r;
      u16* hp = H + (size_t)row * DIM + bn + wcol + l16;
#pragma unroll
      for (int j = 0; j < 4; j++) hp[j * 16] = f2bf(acc[i][j][r]);
    }
  }

  // ---- fused attention dots: partial over this wave's 64 cols ----
  float as_j[4], ad_j[4];
#pragma unroll
  for (int j = 0; j < 4; j++) {
    int col = bn + wcol + j * 16 + l16;
    as_j[j] = atts[col];
    ad_j[j] = attd[col];
  }
  int slot = ((bn >> 7) << 1) + (wcol >> 6);   // 0..7
#pragma unroll
  for (int i = 0; i < 4; i++) {
#pragma unroll
    for (int r = 0; r < 4; r++) {
      float ps = acc[i][0][r] * as_j[0] + acc[i][1][r] * as_j[1]
               + acc[i][2][r] * as_j[2] + acc[i][3][r] * as_j[3];
      float pd = acc[i][0][r] * ad_j[0] + acc[i][1][r] * ad_j[1]
               + acc[i][2][r] * ad_j[2] + acc[i][3][r] * ad_j[3];
#pragma unroll
      for (int d = 1; d < 16; d <<= 1) {
        ps += __shfl_xor(ps, d);
        pd += __shfl_xor(pd, d);
      }
      int row = bm + wrow + i * 16 + quad * 4 + r;
      if (l16 == 0) {
        aspart[slot * MPAD + row] = ps;
        adpart[slot * MPAD + row] = pd;
      }
    }
  }
}

// -------- K_mid: fused dotsum + scatter (writes perm AND perm_src) ---------
__global__ __launch_bounds__(256) void k_mid(const float* __restrict__ aspart,
                                             const float* __restrict__ adpart,
                                             float* __restrict__ a_s,
                                             float* __restrict__ a_d,
                                             const int* __restrict__ ei,
                                             int* __restrict__ cursor,
                                             int* __restrict__ perm,
                                             int* __restrict__ perm_src) {
  int b = blockIdx.x;
  if (b < DOT_BLOCKS) {
    int i = b * 256 + threadIdx.x;
    if (i < N_NODES) {
      float s = 0.f, d = 0.f;
#pragma unroll
      for (int k = 0; k < 8; k++) {
        s += aspart[k * MPAD + i];
        d += adpart[k * MPAD + i];
      }
      a_s[i] = s;
      a_d[i] = d;
    }
  } else {
    int i = (b - DOT_BLOCKS) * 256 + threadIdx.x;
    if (i < ETOT) {
      int d   = (i < NEDGE) ? ei[NEDGE + i] : (i - NEDGE);
      int src = (i < NEDGE) ? ei[i]         : (i - NEDGE);   // coalesced
      int slot = atomicAdd(&cursor[d], 1);
      perm[slot] = i;
      perm_src[slot] = src;
    }
  }
}

// ----- K7: segment softmax + attention dropout + aggregation + stats -------
// oa stored bf16; column/ssq stats computed on the quantized values.
__global__ __launch_bounds__(256) void k_aggregate(
    const int* __restrict__ off, const int* __restrict__ perm,
    const int* __restrict__ perm_src,
    const float* __restrict__ a_s, const float* __restrict__ a_d,
    const u16* __restrict__ h, const float* __restrict__ bias,
    u16* __restrict__ oa, float* __restrict__ colpart,
    float* __restrict__ ssqpart, u32 ka0, u32 ka1) {
  __shared__ float lbuf[4][512];
  int wid = threadIdx.x >> 6;
  int node = blockIdx.x * 4 + wid;
  int lane = threadIdx.x & 63;
  int beg = off[node], end = off[node + 1];
  int deg = end - beg;
  float adn = a_d[node];

  float acc[8] = {0.f, 0.f, 0.f, 0.f, 0.f, 0.f, 0.f, 0.f};

  if (deg <= 64) {
    int idx = beg + lane;
    bool valid = idx < end;
    int s = 0;
    float lg = -3.0e38f;
    u32 keepbits = 0;
    if (valid) {
      int eid = perm[idx];
      s = perm_src[idx];                       // coalesced (was random ei[eid])
      lg = a_s[s] + adn;
      lg = (lg < 0.f) ? 0.2f * lg : lg;
      keepbits = tf_fold(ka0, ka1, (u32)eid);
    }
    float mx = lg;
#pragma unroll
    for (int d = 1; d < 64; d <<= 1) mx = fmaxf(mx, __shfl_xor(mx, d));
    float ee = valid ? expf(lg - mx) : 0.f;
    float ssum = ee;
#pragma unroll
    for (int d = 1; d < 64; d <<= 1) ssum += __shfl_xor(ssum, d);
    float inv_s = 2.5f / (ssum + 1e-16f);
    float w = (valid && ((keepbits >> 9) < 3355444u)) ? ee * inv_s : 0.f;

    // batch-4 ILP gather: 4 independent 1KB row loads in flight.
    int j = 0;
    for (; j + 4 <= deg; j += 4) {
      float wj[4]; int sj[4]; uint4 hv[4];
#pragma unroll
      for (int bq = 0; bq < 4; bq++) {
        wj[bq] = __shfl(w, j + bq);
        sj[bq] = __shfl(s, j + bq);
      }
#pragma unroll
      for (int bq = 0; bq < 4; bq++)
        if (wj[bq] != 0.f)
          hv[bq] = *(const uint4*)(h + (size_t)sj[bq] * DIM + lane * 8);
#pragma unroll
      for (int bq = 0; bq < 4; bq++) {
        if (wj[bq] != 0.f) {
          u32 hw[4] = {hv[bq].x, hv[bq].y, hv[bq].z, hv[bq].w};
#pragma unroll
          for (int p = 0; p < 4; p++) {
            acc[2 * p]     += wj[bq] * bf2f(hw[p] & 0xffffu);
            acc[2 * p + 1] += wj[bq] * bf2f(hw[p] >> 16);
          }
        }
      }
    }
    for (; j < deg; j++) {
      float wjv = __shfl(w, j);
      if (wjv != 0.f) {
        int sjv = __shfl(s, j);
        uint4 hvv = *(const uint4*)(h + (size_t)sjv * DIM + lane * 8);
        u32 hw[4] = {hvv.x, hvv.y, hvv.z, hvv.w};
#pragma unroll
        for (int p = 0; p < 4; p++) {
          acc[2 * p]     += wjv * bf2f(hw[p] & 0xffffu);
          acc[2 * p + 1] += wjv * bf2f(hw[p] >> 16);
        }
      }
    }
  } else {
    float mx = -3.0e38f;
    for (int base = beg; base < end; base += 64) {
      int idx = base + lane;
      if (idx < end) {
        int s = perm_src[idx];
        float lg = a_s[s] + adn;
        lg = (lg < 0.f) ? 0.2f * lg : lg;
        mx = fmaxf(mx, lg);
      }
    }
#pragma unroll
    for (int d = 1; d < 64; d <<= 1) mx = fmaxf(mx, __shfl_xor(mx, d));
    float ssum = 0.f;
    for (int base = beg; base < end; base += 64) {
      int idx = base + lane;
      if (idx < end) {
        int s = perm_src[idx];
        float lg = a_s[s] + adn;
        lg = (lg < 0.f) ? 0.2f * lg : lg;
        ssum += expf(lg - mx);
      }
    }
#pragma unroll
    for (int d = 1; d < 64; d <<= 1) ssum += __shfl_xor(ssum, d);
    float inv_s = 2.5f / (ssum + 1e-16f);
    for (int base = beg; base < end; base += 64) {
      int idx = base + lane;
      float w = 0.f; int s = 0;
      if (idx < end) {
        int eid = perm[idx];
        s = perm_src[idx];
        float lg = a_s[s] + adn;
        lg = (lg < 0.f) ? 0.2f * lg : lg;
        float ee = expf(lg - mx);
        u32 bits = tf_fold(ka0, ka1, (u32)eid);
        if ((bits >> 9) < 3355444u) w = ee * inv_s;
      }
      int cnt = min(64, end - base);
      for (int j = 0; j < cnt; j++) {
        float wj = __shfl(w, j);
        if (wj != 0.f) {
          int sj = __shfl(s, j);
          uint4 hv = *(const uint4*)(h + (size_t)sj * DIM + lane * 8);
          u32 hw[4] = {hv.x, hv.y, hv.z, hv.w};
#pragma unroll
          for (int p = 0; p < 4; p++) {
            acc[2 * p]     += wj * bf2f(hw[p] & 0xffffu);
            acc[2 * p + 1] += wj * bf2f(hw[p] >> 16);
          }
        }
      }
    }
  }

  // epilogue: add bias, quantize to bf16, store oa, stats on quantized vals
  float4 b0 = *(const float4*)(bias + lane * 8);
  float4 b1 = *(const float4*)(bias + lane * 8 + 4);
  float bb[8] = {b0.x, b0.y, b0.z, b0.w, b1.x, b1.y, b1.z, b1.w};
  u32 res[4];
  float vq[8];
#pragma unroll
  for (int p = 0; p < 4; p++) {
    u16 q0 = f2bf(acc[2 * p]     + bb[2 * p]);
    u16 q1 = f2bf(acc[2 * p + 1] + bb[2 * p + 1]);
    res[p] = (u32)q0 | ((u32)q1 << 16);
    vq[2 * p]     = bf2f(q0);
    vq[2 * p + 1] = bf2f(q1);
  }
  *(uint4*)(oa + (size_t)node * DIM + lane * 8) = make_uint4(res[0], res[1], res[2], res[3]);
  *(float4*)&lbuf[wid][lane * 8]     = make_float4(vq[0], vq[1], vq[2], vq[3]);
  *(float4*)&lbuf[wid][lane * 8 + 4] = make_float4(vq[4], vq[5], vq[6], vq[7]);
  __syncthreads();

  int t = threadIdx.x;
  float s0 = 0.f, s1 = 0.f, ssl = 0.f;
#pragma unroll
  for (int w = 0; w < 4; w++) {
    float a = lbuf[w][t], b = lbuf[w][t + 256];
    s0 += a; s1 += b;
    ssl = fmaf(a, a, ssl);
    ssl = fmaf(b, b, ssl);
  }
  colpart[(size_t)blockIdx.x * 512 + t]       = s0;
  colpart[(size_t)blockIdx.x * 512 + 256 + t] = s1;
#pragma unroll
  for (int d = 1; d < 64; d <<= 1) ssl += __shfl_xor(ssl, d);
  __shared__ float wss[4];
  if ((t & 63) == 0) wss[t >> 6] = ssl;
  __syncthreads();
  if (t == 0) ssqpart[blockIdx.x] = wss[0] + wss[1] + wss[2] + wss[3];
}

// ------ K8: reduce partials + (last block) finalize mu/invp, fused ---------
__global__ __launch_bounds__(256) void k_redstats(const float* __restrict__ colpart,
                                                  const float* __restrict__ ssqpart,
                                                  float* __restrict__ colpart2,
                                                  double* __restrict__ ssqp2,
                                                  unsigned int* __restrict__ done,
                                                  float* __restrict__ mu,
                                                  float* __restrict__ invp) {
  int b = blockIdx.x;
  int t = threadIdx.x;
  int r0 = b * RED_ROWS;
  float s0 = 0.f, s1 = 0.f;
  for (int r = r0; r < r0 + RED_ROWS; r++) {
    s0 += colpart[(size_t)r * 512 + t];
    s1 += colpart[(size_t)r * 512 + 256 + t];
  }
  colpart2[(size_t)b * 512 + t]       = s0;
  colpart2[(size_t)b * 512 + 256 + t] = s1;
  float sl = (t < RED_ROWS) ? ssqpart[r0 + t] : 0.f;
#pragma unroll
  for (int d = 1; d < 64; d <<= 1) sl += __shfl_xor(sl, d);
  __shared__ float w4[4];
  if ((t & 63) == 0) w4[t >> 6] = sl;
  __syncthreads();
  if (t == 0) ssqp2[b] = (double)(w4[0] + w4[1] + w4[2] + w4[3]);

  // last-block-done: release own writes, bump counter, last block finalizes
  __threadfence();
  __syncthreads();
  __shared__ unsigned int olds;
  if (t == 0) olds = atomicAdd(done, 1u);
  __syncthreads();
  if (olds == RED_BLOCKS - 1) {
    __threadfence();
    float m0 = 0.f, m1 = 0.f;
    for (int r = 0; r < RED_BLOCKS; r++) {
      m0 += colpart2[(size_t)r * 512 + t];
      m1 += colpart2[(size_t)r * 512 + 256 + t];
    }
    m0 *= (1.0f / 30000.0f);
    m1 *= (1.0f / 30000.0f);
    mu[t]       = m0;
    mu[t + 256] = m1;
    double p = (double)m0 * (double)m0 + (double)m1 * (double)m1;
#pragma unroll
    for (int d = 1; d < 64; d <<= 1) p += __shfl_xor(p, d);
    __shared__ double sred[4];
    __shared__ double ssqs;
    if ((t & 63) == 0) sred[t >> 6] = p;
    if (t < 64) {
      double sq = (t < RED_BLOCKS) ? ssqp2[t] : 0.0;
#pragma unroll
      for (int d = 1; d < 64; d <<= 1) sq += __shfl_xor(sq, d);
      if (t == 0) ssqs = sq;
    }
    __syncthreads();
    if (t == 0) {
      double smu2 = sred[0] + sred[1] + sred[2] + sred[3];
      double centered = ssqs - 30000.0 * smu2;
      double mean = centered * (1.0 / 30000.0);
      if (!(mean >= 0.0)) mean = 0.0;
      float rn = sqrtf(1e-6f + (float)mean);
      invp[0] = 1.0f / rn;
    }
  }
}

// ---------------- K10: center, scale, relu (bf16 oa -> fp32 out) -----------
__global__ __launch_bounds__(256) void k_finalout(const u16* __restrict__ oa,
                                                  const float* __restrict__ mu,
                                                  const float* __restrict__ invp,
                                                  float* __restrict__ out) {
  size_t gid = (size_t)blockIdx.x * 256 + threadIdx.x;
  size_t i0 = gid * 8;
  if (i0 >= (size_t)N_NODES * DIM) return;
  float inv = invp[0];
  int j = (int)(i0 & (DIM - 1));
  uint4 v = *(const uint4*)(oa + i0);
  u32 w[4] = {v.x, v.y, v.z, v.w};
  float o[8];
#pragma unroll
  for (int p = 0; p < 4; p++) {
    float z0 = (bf2f(w[p] & 0xffffu) - mu[j + 2 * p]) * inv;
    float z1 = (bf2f(w[p] >> 16)     - mu[j + 2 * p + 1]) * inv;
    o[2 * p]     = (z0 < 0.f) ? 0.f : z0;
    o[2 * p + 1] = (z1 < 0.f) ? 0.f : z1;
  }
  *(float4*)(out + i0)     = make_float4(o[0], o[1], o[2], o[3]);
  *(float4*)(out + i0 + 4) = make_float4(o[4], o[5], o[6], o[7]);
}

// ---------------------------------------------------------------------------
extern "C" void kernel_launch(void* const* d_in, const int* in_sizes, int n_in,
                              void* d_out, int out_size, void* d_ws, size_t ws_size,
                              hipStream_t stream) {
  const float* x    = (const float*)d_in[0];
  const int*   ei   = (const int*)d_in[1];
  const float* W    = (const float*)d_in[2];
  const float* atts = (const float*)d_in[3];
  const float* attd = (const float*)d_in[4];
  const float* bias = (const float*)d_in[5];
  float* out = (float*)d_out;
  char* ws = (char*)d_ws;

  // oa overlays xd at ws+0 (xd dead after gemm). colpart/ssqpart/perm_src
  // live in the [34M, 61.44M) dead gap.
  u16*   xd      = (u16*)(ws + 0);             // 30,801,920
  u16*   oa      = (u16*)(ws + 0);             // 30,720,000 (overlay)
  float* aspart  = (float*)(ws + 32000000);    //   962,560
  float* adpart  = (float*)(ws + 33000000);    //   962,560
  float* colpart2 = (float*)(ws + 34000000);   //   122,880
  double* ssqp2  = (double*)(ws + 34130000);   //       480
  unsigned int* done  = (unsigned int*)(ws + 34140000);   // 4
  float* colpart = (float*)(ws + 35000000);    // 7500*512*4 = 15,360,000
  float* ssqpart = (float*)(ws + 50500000);    //    30,000
  int*   perm_src = (int*)(ws + 51000000);     // 1,320,000 -> 52.32M
  u16*   h       = (u16*)(ws + 61440000);      // 30,801,920
  u16*   Wt      = (u16*)(ws + 92241920);      //    524,288
  float* a_s     = (float*)(ws + 92766208);    //    120,064
  float* a_d     = (float*)(ws + 92886272);    //    120,064
  int*   counts  = (int*)(ws + 93006336);
  int*   offs    = (int*)(ws + 93126400);
  int*   cursor  = (int*)(ws + 93246464);
  int*   perm    = (int*)(ws + 93366528);      //  1,320,000
  float* mu      = (float*)(ws + 94688576);
  float* invp    = (float*)(ws + 94690688);    // end 94,690,752

  u32 kf0, kf1, ka0, ka1;
  threefry2x32(0u, 42u, 0u, 0u, kf0, kf1);
  threefry2x32(0u, 42u, 0u, 1u, ka0, ka1);

  hipMemsetAsync(counts, 0, 120064, stream);

  // L1: cvtW + dropout + hist; block 0 resets the done counter.
  k_pre<<<CVT_BLOCKS + DROP_BLOCKS + HIST_BLOCKS, 256, 0, stream>>>(
      W, Wt, x, xd, ei, counts, done, kf0, kf1);
  // L2: scan (block 0) + swizzled gemm (blocks 1..940)
  k_gemm<<<GEMM_BLOCKS + 1, 256, 0, stream>>>(xd, Wt, h, atts, attd,
                                              aspart, adpart, counts, offs, cursor);
  // L3: dotsum + scatter (perm + perm_src)
  k_mid<<<DOT_BLOCKS + HIST_BLOCKS, 256, 0, stream>>>(aspart, adpart, a_s, a_d,
                                                      ei, cursor, perm, perm_src);
  // L4: aggregate (stats -> ws colpart/ssqpart)
  k_aggregate<<<AGG_BLOCKS, 256, 0, stream>>>(offs, perm, perm_src, a_s, a_d,
                                              h, bias, oa, colpart, ssqpart,
                                              ka0, ka1);
  // L5: reduce + fused finalize (last-block-done)
  k_redstats<<<RED_BLOCKS, 256, 0, stream>>>(colpart, ssqpart, colpart2, ssqp2,
                                             done, mu, invp);
  // L6: center/scale/relu
  k_finalout<<<7500, 256, 0, stream>>>(oa, mu, invp, out);
}